// Round 3
// baseline (68.756 us; speedup 1.0000x reference)
//
#include <hip/hip_runtime.h>

#define HDIM 96
#define WDIM 96
#define HWSZ (HDIM * WDIM)   // 9216 = 9 * 1024 exactly
#define NPAIRS 32
#define NONE_DIST 1000       // "no set bit" sentinel distance
#define NONE_D 1000000       // sentinel squared distance (> 95^2+95^2)
#define DIST_NORM 102400.0f  // 320^2

// Distance from y to the nearest set bit at index >= y in a 96-bit mask
// (lo = bits 0..63, hi = bits 64..95). NONE_DIST if none.
__device__ __forceinline__ int nsb96(unsigned long long lo, unsigned long long hi, int y) {
    unsigned long long a, b;
    if (y == 0)      { a = lo;                                b = hi; }
    else if (y < 64) { a = (lo >> y) | (hi << (64 - y));      b = hi >> y; }
    else             { a = hi >> (y - 64);                    b = 0ull; }
    if (a) return (int)__ffsll(a) - 1;
    if (b) return 64 + (int)__ffsll(b) - 1;
    return NONE_DIST;
}

// One block per (b,c) pair, fused final reduction via last-block ticket.
// 1) stage P (row-major bytes) and G (transposed ints, stride 97) in LDS
// 2) GT edge masks as 96-bit column bitmasks via __ballot (+ bit-reversed copy)
// 3) d1[y][x] = min_{y': gm[y'][x]} (y-y')^2 in O(1)/pixel via nsb96
// 4) directed Hausdorff: per pred-edge pixel, outward row scan with early exit
// 5) per-pair int value -> device atomicAdd; last block divides and writes out
__global__ __launch_bounds__(1024) void hausdorff_fused_kernel(
    const float* __restrict__ pred, const float* __restrict__ GT,
    int* __restrict__ ws /* ws[0]=acc, ws[1]=ticket (memset to 0) */,
    float* __restrict__ out) {
    const int pair = blockIdx.x;                // pair = b*4 + c
    const int padi = ((pair & 3) == 0) ? 1 : 0; // channel 0 pads with 1
    const float* __restrict__ P = pred + (size_t)pair * HWSZ;
    const float* __restrict__ G = GT + (size_t)pair * HWSZ;

    __shared__ int GbT[WDIM * (HDIM + 1)];      // transposed, stride 97 (bank-friendly)
    __shared__ unsigned char Pb[HWSZ];          // pred binary, row-major
    __shared__ int d1[HWSZ];                    // per-column min (y-y')^2 (int, exact)
    __shared__ unsigned long long c_lo[WDIM], c_hi[WDIM];  // column masks
    __shared__ unsigned long long r_lo[WDIM], r_hi[WDIM];  // bit-reversed column masks
    __shared__ int wmax[16], wflag[16];

    const int tid = threadIdx.x;
    const int lane = tid & 63;
    const int wv = tid >> 6;

    // ---- stage inputs to LDS (coalesced global reads)
    for (int k = 0; k < 9; ++k) {
        const int i = tid + (k << 10);
        const int y = i / WDIM, x = i - y * WDIM;
        Pb[i] = (P[i] != 0.0f);
        GbT[x * 97 + y] = (G[i] != 0.0f);       // bank = (x+y)%32: conflict-free
    }
    __syncthreads();

    // ---- GT edge masks as column bitmasks (wave wv handles columns wv, wv+16, ...)
    int ganyw = 0;   // wave-uniform: any GT edge bit in this wave's columns
    for (int x = wv; x < WDIM; x += 16) {
        int e0;
        {
            const int y = lane;
            const int c  = GbT[x * 97 + y];
            const int dn = GbT[x * 97 + y + 1];               // y+1 <= 64 < 96 always
            const int up = (y > 0)        ? GbT[x * 97 + y - 1] : padi;
            const int rt = (x + 1 < WDIM) ? GbT[(x + 1) * 97 + y] : padi;
            const int lt = (x > 0)        ? GbT[(x - 1) * 97 + y] : padi;
            e0 = (4 * c - (dn + up + rt + lt)) > 0;
        }
        const unsigned long long lo = __ballot(e0);
        int e1 = 0;
        if (lane < 32) {
            const int y = 64 + lane;
            const int c  = GbT[x * 97 + y];
            const int dn = (y + 1 < HDIM) ? GbT[x * 97 + y + 1] : padi;
            const int up = GbT[x * 97 + y - 1];
            const int rt = (x + 1 < WDIM) ? GbT[(x + 1) * 97 + y] : padi;
            const int lt = (x > 0)        ? GbT[(x - 1) * 97 + y] : padi;
            e1 = (4 * c - (dn + up + rt + lt)) > 0;
        }
        const unsigned long long hi = __ballot(e1) & 0xffffffffull;
        ganyw |= ((lo | hi) != 0ull);
        if (lane == 0) {
            c_lo[x] = lo;
            c_hi[x] = hi;
            // 96-bit reverse: rev = bitrev128(hi:lo) >> 32
            const unsigned long long rl = __brevll(hi), rh = __brevll(lo);
            r_lo[x] = (rl >> 32) | (rh << 32);
            r_hi[x] = rh >> 32;
        }
    }
    __syncthreads();

    // ---- d1: nearest set bit in column, squared (O(1) per pixel)
    for (int k = 0; k < 9; ++k) {
        const int i = tid + (k << 10);
        const int y = i / WDIM, x = i - y * WDIM;
        const int dd = nsb96(c_lo[x], c_hi[x], y);
        const int du = nsb96(r_lo[x], r_hi[x], 95 - y);
        const int n = min(dd, du);
        d1[i] = (n >= NONE_DIST) ? NONE_D : n * n;
    }
    __syncthreads();

    // ---- pass 2: pred edge mask + outward row scan with early exit
    int bestMax = 0;   // mins >= 0, so 0 sentinel matches reference
    int anyP = 0;
    for (int k = 0; k < 9; ++k) {
        const int i = tid + (k << 10);
        const int y = i / WDIM, x = i - y * WDIM;
        const int c  = Pb[i];
        const int dn = (y + 1 < HDIM) ? Pb[i + WDIM] : padi;
        const int up = (y > 0)        ? Pb[i - WDIM] : padi;
        const int rt = (x + 1 < WDIM) ? Pb[i + 1]    : padi;
        const int lt = (x > 0)        ? Pb[i - 1]    : padi;
        const int pm = (4 * c - (dn + up + rt + lt)) > 0;
        anyP |= pm;
        if (pm) {
            int best = d1[i];
            for (int r = 1; r < WDIM; ++r) {
                const int rr = r * r;
                if (rr >= best) break;           // no farther x' can improve
                if (x - r >= 0)   best = min(best, d1[i - r] + rr);
                if (x + r < WDIM) best = min(best, d1[i + r] + rr);
            }
            bestMax = max(bestMax, best);
        }
    }

    // ---- wave reduce (64 lanes), then cross-wave via LDS
    for (int off = 32; off > 0; off >>= 1) {
        bestMax = max(bestMax, __shfl_down(bestMax, off));
        anyP |= __shfl_down(anyP, off);
    }
    if (lane == 0) {
        wmax[wv] = bestMax;
        wflag[wv] = ((anyP ? 1 : 0) << 1) | (ganyw ? 1 : 0);
    }
    __syncthreads();

    // ---- per-pair value -> global int accumulator; last block finalizes
    if (tid == 0) {
        int m = 0, fP = 0, fG = 0;
        for (int w = 0; w < 16; ++w) {
            m = max(m, wmax[w]);
            fP |= (wflag[w] >> 1) & 1;
            fG |= wflag[w] & 1;
        }
        const int val = (fP && fG) ? m : 0;
        atomicAdd(&ws[0], val);            // device-scope by default on CDNA
        __threadfence();                   // make acc visible before ticket
        const int old = atomicAdd(&ws[1], 1);
        if (old == NPAIRS - 1) {           // last arriver finalizes (no spin)
            __threadfence();
            const int total = atomicAdd(&ws[0], 0);  // device-scope read
            out[0] = (float)total / DIST_NORM;       // exact int -> same divide as ref
        }
    }
}

extern "C" void kernel_launch(void* const* d_in, const int* in_sizes, int n_in,
                              void* d_out, int out_size, void* d_ws, size_t ws_size,
                              hipStream_t stream) {
    const float* pred = (const float*)d_in[0];
    const float* GT = (const float*)d_in[1];
    float* out = (float*)d_out;
    int* ws = (int*)d_ws;

    // zero acc + ticket (ws is re-poisoned to 0xAA before every timed launch);
    // hipMemsetAsync is graph-capturable (becomes a memset node)
    hipMemsetAsync(ws, 0, 2 * sizeof(int), stream);
    hausdorff_fused_kernel<<<NPAIRS, 1024, 0, stream>>>(pred, GT, ws, out);
}

// Round 5
// 66.769 us; speedup vs baseline: 1.0298x; 1.0298x over previous
//
#include <hip/hip_runtime.h>

#define HDIM 96
#define WDIM 96
#define HWSZ 9216            // 96*96 = 9 * 1024
#define NPAIRS 32
#define NONE_D 1000000       // sentinel squared distance (> 95^2 + 95^2)
#define DIST_NORM 102400.0f  // 320^2
#define RSTRIDE 25           // u32s per staged row (100 B): l*25 % 32 hits all banks

// Distance from y to the nearest set bit at index >= y in a 96-bit mask
// (lo = bits 0..63, hi = bits 64..95). 1000 if none.
__device__ __forceinline__ int nsb96(unsigned long long lo, unsigned long long hi, int y) {
    unsigned long long a, b;
    if (y == 0)      { a = lo;                                b = hi; }
    else if (y < 64) { a = (lo >> y) | (hi << (64 - y));      b = hi >> y; }
    else             { a = hi >> (y - 64);                    b = 0ull; }
    if (a) return (int)__ffsll(a) - 1;
    if (b) return 64 + (int)__ffsll(b) - 1;
    return 1000;
}

// One block per (b,c) pair, fused final reduction via last-block ticket.
// All edge-mask math done on 96-bit column bitmasks (binary inputs):
//   edge = C & ~(U & D & L & R)   [U/D = y-shifts with pad, L/R = neighbor cols]
__global__ __launch_bounds__(1024) void hausdorff_fused_kernel(
    const float* __restrict__ pred, const float* __restrict__ GT,
    int* __restrict__ ws /* ws[0]=acc, ws[1]=ticket (memset to 0) */,
    float* __restrict__ out) {
    const int pair = blockIdx.x;                 // pair = b*4 + c
    const int padi = ((pair & 3) == 0) ? 1 : 0;  // channel 0 pads with 1
    const float4* __restrict__ P4 = (const float4*)(pred + (size_t)pair * HWSZ);
    const float4* __restrict__ G4 = (const float4*)(GT + (size_t)pair * HWSZ);

    __shared__ unsigned int PbW[HDIM * RSTRIDE];   // packed binary bytes, 100B/row
    __shared__ unsigned int GbW[HDIM * RSTRIDE];
    __shared__ unsigned long long Pc_lo[96], Pc_hi[96];   // raw column masks
    __shared__ unsigned long long Gc_lo[96], Gc_hi[96];
    __shared__ unsigned long long EP_lo[96], EP_hi[96];   // edge column masks
    __shared__ unsigned long long EG_lo[96], EG_hi[96];
    __shared__ unsigned long long RG_lo[96], RG_hi[96];   // bit-reversed EG
    __shared__ int d1[HWSZ];                              // column DT, squared
    __shared__ int wmax[16];
    __shared__ int sAnyP, sAnyG;

    const int tid = threadIdx.x;
    const int lane = tid & 63;
    const int wv = tid >> 6;
    if (tid == 0) { sAnyP = 0; sAnyG = 0; }

    // ---- stage: coalesced float4 loads -> packed bytes in LDS
    for (int q = tid; q < 2304; q += 1024) {     // 2304 float4s per image
        const int y = q / 24, xq = q - y * 24;   // 24 float4s per row
        const float4 p = P4[q], g = G4[q];
        const unsigned int pw = (p.x != 0.f ? 1u : 0u) | (p.y != 0.f ? 1u << 8 : 0u) |
                                (p.z != 0.f ? 1u << 16 : 0u) | (p.w != 0.f ? 1u << 24 : 0u);
        const unsigned int gw = (g.x != 0.f ? 1u : 0u) | (g.y != 0.f ? 1u << 8 : 0u) |
                                (g.z != 0.f ? 1u << 16 : 0u) | (g.w != 0.f ? 1u << 24 : 0u);
        PbW[y * RSTRIDE + xq] = pw;
        GbW[y * RSTRIDE + xq] = gw;
    }
    __syncthreads();

    // ---- ballot-transpose: raw 96-bit column masks (wave wv -> columns 6wv..6wv+5)
    for (int x = 6 * wv; x < 6 * wv + 6; ++x) {
        const int xw = x >> 2, sh = (x & 3) * 8;
        const int pb = (PbW[lane * RSTRIDE + xw] >> sh) & 1;
        const int gb = (GbW[lane * RSTRIDE + xw] >> sh) & 1;
        const unsigned long long plo = __ballot(pb);
        const unsigned long long glo = __ballot(gb);
        int pbh = 0, gbh = 0;
        if (lane < 32) {
            pbh = (PbW[(64 + lane) * RSTRIDE + xw] >> sh) & 1;
            gbh = (GbW[(64 + lane) * RSTRIDE + xw] >> sh) & 1;
        }
        const unsigned long long phi = __ballot(pbh) & 0xffffffffull;
        const unsigned long long ghi = __ballot(gbh) & 0xffffffffull;
        if (lane == 0) {
            Pc_lo[x] = plo; Pc_hi[x] = phi;
            Gc_lo[x] = glo; Gc_hi[x] = ghi;
        }
    }
    __syncthreads();

    // ---- edge masks, 96-bit bitwise (threads 0..95: P; threads 128..223: G)
    if (tid < 96 || (tid >= 128 && tid < 224)) {
        const bool isP = (tid < 96);
        const int x = isP ? tid : tid - 128;
        const unsigned long long* Clo = isP ? Pc_lo : Gc_lo;
        const unsigned long long* Chi = isP ? Pc_hi : Gc_hi;
        const unsigned long long clo = Clo[x], chi = Chi[x];
        // U: bit y = value(y-1); pad at bit 0
        const unsigned long long ulo = (clo << 1) | (unsigned long long)padi;
        const unsigned long long uhi = ((chi << 1) | (clo >> 63)) & 0xffffffffull;
        // D: bit y = value(y+1); pad at bit 95 (hi bit 31)
        const unsigned long long dlo = (clo >> 1) | (chi << 63);
        const unsigned long long dhi = (chi >> 1) | ((unsigned long long)padi << 31);
        unsigned long long llo, lhi, rlo, rhi;
        if (x > 0)  { llo = Clo[x - 1]; lhi = Chi[x - 1]; }
        else        { llo = padi ? ~0ull : 0ull; lhi = padi ? 0xffffffffull : 0ull; }
        if (x < 95) { rlo = Clo[x + 1]; rhi = Chi[x + 1]; }
        else        { rlo = padi ? ~0ull : 0ull; rhi = padi ? 0xffffffffull : 0ull; }
        const unsigned long long elo = clo & ~(ulo & dlo & llo & rlo);
        const unsigned long long ehi = (chi & ~(uhi & dhi & lhi & rhi)) & 0xffffffffull;
        if (isP) {
            EP_lo[x] = elo; EP_hi[x] = ehi;
            if (elo | ehi) sAnyP = 1;            // benign same-value race
        } else {
            EG_lo[x] = elo; EG_hi[x] = ehi;
            const unsigned long long rl = __brevll(ehi), rh = __brevll(elo);
            RG_lo[x] = (rl >> 32) | (rh << 32);  // bit j = E bit (95-j)
            RG_hi[x] = rh >> 32;
            if (elo | ehi) sAnyG = 1;
        }
    }
    __syncthreads();

    // ---- d1: nearest GT-edge in column, squared (O(1)/pixel)
    for (int k = 0; k < 9; ++k) {
        const int i = tid + (k << 10);
        const int y = i / WDIM, x = i - y * WDIM;
        const int dd = nsb96(EG_lo[x], EG_hi[x], y);
        const int du = nsb96(RG_lo[x], RG_hi[x], 95 - y);
        const int n = min(dd, du);
        d1[i] = (n >= 1000) ? NONE_D : n * n;
    }
    __syncthreads();

    // ---- pass 2: pred-edge pixels -> outward row scan with early exit
    int bestMax = 0;
    const bool live = (sAnyP != 0) && (sAnyG != 0);
    if (live) {
        for (int k = 0; k < 9; ++k) {
            const int i = tid + (k << 10);
            const int y = i / WDIM, x = i - y * WDIM;
            const unsigned long long ep = (y < 64) ? EP_lo[x] : EP_hi[x];
            if ((ep >> (y & 63)) & 1) {
                int best = d1[i];
                for (int r = 1; r < WDIM; ++r) {
                    const int rr = r * r;
                    if (rr >= best) break;       // no farther x' can improve
                    if (x - r >= 0)   best = min(best, d1[i - r] + rr);
                    if (x + r < WDIM) best = min(best, d1[i + r] + rr);
                }
                bestMax = max(bestMax, best);
            }
        }
    }

    // ---- wave reduce (64 lanes), then cross-wave via LDS
    for (int off = 32; off > 0; off >>= 1)
        bestMax = max(bestMax, __shfl_down(bestMax, off));
    if (lane == 0) wmax[wv] = bestMax;
    __syncthreads();

    // ---- per-pair value -> global int accumulator; last block finalizes
    if (tid == 0) {
        int m = 0;
        for (int w = 0; w < 16; ++w) m = max(m, wmax[w]);
        const int val = live ? m : 0;
        atomicAdd(&ws[0], val);            // device-scope by default on CDNA
        __threadfence();                   // make acc visible before ticket
        const int old = atomicAdd(&ws[1], 1);
        if (old == NPAIRS - 1) {           // last arriver finalizes (no spin)
            __threadfence();
            const int total = atomicAdd(&ws[0], 0);  // device-scope read
            out[0] = (float)total / DIST_NORM;       // exact int, same divide as ref
        }
    }
}

extern "C" void kernel_launch(void* const* d_in, const int* in_sizes, int n_in,
                              void* d_out, int out_size, void* d_ws, size_t ws_size,
                              hipStream_t stream) {
    const float* pred = (const float*)d_in[0];
    const float* GT = (const float*)d_in[1];
    float* out = (float*)d_out;
    int* ws = (int*)d_ws;

    // zero acc + ticket (8 bytes; graph-capturable memset node)
    hipMemsetAsync(ws, 0, 2 * sizeof(int), stream);
    hausdorff_fused_kernel<<<NPAIRS, 1024, 0, stream>>>(pred, GT, ws, out);
}